// Round 11
// baseline (254.247 us; speedup 1.0000x reference)
//
#include <hip/hip_runtime.h>
#include <hip/hip_bf16.h>
#include <cstdint>

typedef _Float16 f16;
typedef f16 f16x8 __attribute__((ext_vector_type(8)));
typedef f16 f16x4 __attribute__((ext_vector_type(4)));
typedef float f32x4 __attribute__((ext_vector_type(4)));

#define MFMA16(a, b, c) __builtin_amdgcn_mfma_f32_16x16x32_f16((a), (b), (c), 0, 0, 0)

constexpr int Bc = 4, Sc = 2048, Dc = 1024, Hc = 16, DHc = 64;

typedef __attribute__((address_space(1))) const uint32_t gbl_u32;
typedef __attribute__((address_space(3))) uint32_t lds_u32;
__device__ __forceinline__ void gld_lds16(const void* g, void* l) {
  __builtin_amdgcn_global_load_lds((gbl_u32*)g, (lds_u32*)l, 16, 0, 0);
}

// ---------------------------------------------------------------------------
// Kernel 1: cast+transpose weights: W fp32 [K=1024][N=1024] -> Wt f16 [z][N][K]
// (viewed by the GEMM as one [3072][1024] B^T matrix)
// ---------------------------------------------------------------------------
__global__ __launch_bounds__(256) void cast_w_kernel(
    const float* __restrict__ Wq, const float* __restrict__ Wk,
    const float* __restrict__ Wv, f16* __restrict__ Wt) {
  __shared__ __align__(16) f16 T[64][66];
  const int z = blockIdx.z;
  const float* W = (z == 0) ? Wq : (z == 1) ? Wk : Wv;
  const int n0 = blockIdx.x * 64, k0 = blockIdx.y * 64;
  const int t = threadIdx.x;
#pragma unroll
  for (int p = 0; p < 4; p++) {
    int idx = t + p * 256;
    int r = idx >> 4, c = idx & 15;
    float4 v = *(const float4*)(W + (size_t)(k0 + r) * Dc + n0 + c * 4);
    T[r][c * 4 + 0] = (f16)v.x;
    T[r][c * 4 + 1] = (f16)v.y;
    T[r][c * 4 + 2] = (f16)v.z;
    T[r][c * 4 + 3] = (f16)v.w;
  }
  __syncthreads();
#pragma unroll
  for (int p = 0; p < 2; p++) {
    int idx = t + p * 256;
    int n = idx >> 3, c = idx & 7;
    f16x8 tmp;
#pragma unroll
    for (int j = 0; j < 8; j++) tmp[j] = T[c * 8 + j][n];
    *(f16x8*)(Wt + ((size_t)z * Dc + n0 + n) * Dc + k0 + c * 8) = tmp;
  }
}

// ---------------------------------------------------------------------------
// Kernel 1b: cast X fp32 -> f16.
// ---------------------------------------------------------------------------
__global__ __launch_bounds__(256) void cast_x_kernel(const float* __restrict__ X,
                                                     f16* __restrict__ X16) {
  size_t i = ((size_t)blockIdx.x * 256 + threadIdx.x) * 8;
  float4 a = *(const float4*)(X + i);
  float4 b = *(const float4*)(X + i + 4);
  f16x8 h;
  h[0] = (f16)a.x; h[1] = (f16)a.y; h[2] = (f16)a.z; h[3] = (f16)a.w;
  h[4] = (f16)b.x; h[5] = (f16)b.y; h[6] = (f16)b.z; h[7] = (f16)b.w;
  *(f16x8*)(X16 + i) = h;
}

// ---------------------------------------------------------------------------
// Kernel 2 (R11): R2/R10's fused QKV GEMM (BK=32 m97 structure) + ONE delta:
// the z<2 (Q/K) epilogue goes through an LDS transpose. Evidence: R9 proved
// the Q/K store pattern is first-order (+/-21 us); baseline = 64 scalar 2B
// stores/thread (4 scattered 32B runs per instr); R9's d-packed variant = 64
// lines/instr (worse). LDS route wins BOTH axes: 16 ds_write_b16 per mt
// into Cbuf[32][136] (pad -> quad-row writes 2-way/free, rows 16B-aligned),
// barrier, then each thread re-reads one 32B d-contiguous run (2x b128) and
// issues 2 COALESCED 16B global stores into 128B-contiguous output rows.
// Global store instrs for Q/K: 64 -> 8 per thread. V epilogue unchanged.
// Staging LDS (dead after K-loop) is reused as Cbuf; LDS stays 16 KB.
// XCD-chunked swizzle: lin&7 = XCD, m-tile innermost.
// Q pre-scaled by 0.125*log2(e) for the flash exp2 path.
// ---------------------------------------------------------------------------
__global__ __launch_bounds__(256) void qkv_gemm_kernel(
    const f16* __restrict__ X16, const f16* __restrict__ Wt,
    const float* __restrict__ bq, const float* __restrict__ bk,
    const float* __restrict__ bv, f16* __restrict__ Qo, f16* __restrict__ Ko,
    f16* __restrict__ Vo) {
  const int lin = blockIdx.x;               // 1536 blocks
  const int xcd = lin & 7, jj = lin >> 3;   // jj in [0,192)
  const int bn = jj >> 3;                   // 0..23 (n-tile over fused N=3072)
  const int bm = (xcd << 3) | (jj & 7);     // 0..63 (m-tile; inner index)
  const int z = bn >> 3;
  const int n0 = (bn & 7) * 128;            // col base within this z
  const int m0 = bm * 128;
  const f16* W = Wt + (size_t)bn * 128 * Dc;  // rows [bn*128, bn*128+128)
  const float* bias = (z == 0) ? bq : (z == 1) ? bk : bv;

  __shared__ __align__(16) f16 SMEM[8192];  // 16 KB: staging / epilogue Cbuf
  f16* Xs = SMEM;                           // [128*32]
  f16* Ws = SMEM + 4096;                    // [128*32]

  const int t = threadIdx.x;
  const int wave = t >> 6, lane = t & 63;
  const int l16 = lane & 15, quad = lane >> 4;
  const int wm = (wave >> 1) * 64, wn = (wave & 1) * 64;

  f32x4 acc[4][4];
#pragma unroll
  for (int i = 0; i < 4; i++)
#pragma unroll
    for (int j = 0; j < 4; j++) acc[i][j] = (f32x4){0.f, 0.f, 0.f, 0.f};

  for (int k0 = 0; k0 < Dc; k0 += 32) {
#pragma unroll
    for (int p = 0; p < 2; p++) {
      int cb = p * 256 + wave * 64;
      int chunk = cb + lane;
      int row = chunk >> 2, c8 = (chunk & 3) * 8;
      gld_lds16(X16 + (size_t)(m0 + row) * Dc + k0 + c8, Xs + (size_t)cb * 8);
      gld_lds16(W + (size_t)row * Dc + k0 + c8, Ws + (size_t)cb * 8);
    }
    __syncthreads();

    f16x8 aF[4], bF[4];
#pragma unroll
    for (int mt = 0; mt < 4; mt++)
      aF[mt] = *(const f16x8*)(&Xs[(wm + mt * 16 + l16) * 32 + quad * 8]);
#pragma unroll
    for (int nt = 0; nt < 4; nt++)
      bF[nt] = *(const f16x8*)(&Ws[(wn + nt * 16 + l16) * 32 + quad * 8]);
#pragma unroll
    for (int mt = 0; mt < 4; mt++)
#pragma unroll
      for (int nt = 0; nt < 4; nt++)
        acc[mt][nt] = MFMA16(aF[mt], bF[nt], acc[mt][nt]);
    __syncthreads();
  }

  if (z != 2) {
    // ---- LDS-transpose epilogue for Q/K ----
    const float sc = (z == 0) ? 0.18033688011112042f : 1.0f;  // Q: 0.125*log2e
    f16* O = (z == 0) ? Qo : Ko;
    const int wh = wave >> 1;  // which 64-row s-half this wave produced
    float bv4[4];
#pragma unroll
    for (int nt = 0; nt < 4; nt++) bv4[nt] = bias[n0 + wn + nt * 16 + l16];
    // read-phase indices (same every mt)
    const int ridx = t >> 3, sub = t & 7;
    const int c0 = sub * 16;
    const int h = (n0 + c0) >> 6, d0 = c0 & 63;
#pragma unroll
    for (int mt = 0; mt < 4; mt++) {
#pragma unroll
      for (int nt = 0; nt < 4; nt++) {
        int c = wn + nt * 16 + l16;
#pragma unroll
        for (int r = 0; r < 4; r++) {
          int idx = wh * 16 + quad * 4 + r;
          SMEM[idx * 136 + c] = (f16)((acc[mt][nt][r] + bv4[nt]) * sc);
        }
      }
      __syncthreads();
      int s = m0 + (ridx >> 4) * 64 + mt * 16 + (ridx & 15);
      int b = s >> 11, sl = s & 2047;
      f16* dst = O + (((size_t)(b * Hc + h)) * Sc + sl) * DHc + d0;
      const f16* srcp = &SMEM[ridx * 136 + c0];
      f16x8 v0 = *(const f16x8*)(srcp);
      f16x8 v1 = *(const f16x8*)(srcp + 8);
      *(f16x8*)(dst) = v0;
      *(f16x8*)(dst + 8) = v1;
      __syncthreads();
    }
  } else {
    // ---- V epilogue (unchanged): f16x4 pack along s into Vt [bh][d][s] ----
#pragma unroll
    for (int nt = 0; nt < 4; nt++) {
      int col = n0 + wn + nt * 16 + l16;
      float bval = bias[col];
      int h = col >> 6, d = col & 63;
#pragma unroll
      for (int mt = 0; mt < 4; mt++) {
        int m = m0 + wm + mt * 16 + quad * 4;
        int b = m >> 11, sbase = m & 2047;
        f16x4 pk;
#pragma unroll
        for (int r = 0; r < 4; r++) pk[r] = (f16)(acc[mt][nt][r] + bval);
        *(f16x4*)(Vo + (((size_t)(b * Hc + h)) * DHc + d) * Sc + sbase) = pk;
      }
    }
  }
}

// ---------------------------------------------------------------------------
// Kernel 3 (R11): flash attention — unchanged from R3/R9/R10 (measured
// 98-102 us): 32 queries/wave, 1024 blocks = 4/CU, XCD-chunked bh,
// register-resident P via KEY-PERMUTED K staging, mask in LDS pre-scaled by
// log2(e), l row-sums on the MFMA pipe.
// ---------------------------------------------------------------------------
__global__ __launch_bounds__(256) void flash_kernel(
    const f16* __restrict__ Q, const f16* __restrict__ K,
    const f16* __restrict__ Vt, const float* __restrict__ mask,
    float* __restrict__ out) {
  const int lin = blockIdx.x;               // 1024 blocks
  const int xcd = lin & 7, jj = lin >> 3;   // jj in [0,128)
  const int bh = (xcd << 3) | (jj & 7);     // 0..63 (inner: bh cycles fastest)
  const int qt = jj >> 3;                   // 0..15
  const int b = bh >> 4, h = bh & 15;
  const int t = threadIdx.x;
  const int wave = t >> 6, lane = t & 63;
  const int l16 = lane & 15, quad = lane >> 4;
  const int qbase = qt * 128 + wave * 32;

  __shared__ __align__(16) f16 Ks[2][4096];  // [buf][half*2048+row*32+oct*8]
  __shared__ __align__(16) f16 Vs[2][4096];  // [buf][kh*2048+dh*32+oct*8]
  __shared__ __align__(16) float Ms[2048];   // mask row * log2(e)

  const f16* Kb = K + (size_t)bh * Sc * DHc;
  const f16* Vb = Vt + (size_t)bh * DHc * Sc;

  constexpr float L2E = 1.44269504088896340736f;

  // swizzled b128 read position (same for K and V frags)
  const int qsw8 = (quad ^ ((l16 >> 1) & 3)) * 8;

  // octet i -> half=i>>8, row=(i>>2)&63, pos q8=i&3 holds global octet
  // q8^((row>>1)&3). K rows are PERMUTED: staged row k holds global key
  // phys(k): [n1 n0 q1 q0 r1 r0] -> [n1 q1 q0 n0 r1 r0].
  const f16* kp[2];
  const f16* vp[2];
  int ldsOff[2];
#pragma unroll
  for (int p = 0; p < 2; p++) {
    int cb = p * 256 + wave * 64;  // wave-uniform octet base
    int i = cb + lane;
    int half = i >> 8, row = (i >> 2) & 63, q8 = i & 3;
    int q8g = q8 ^ ((row >> 1) & 3);
    int g = (row & 32) | ((row & 12) << 1) | ((row & 16) >> 2) | (row & 3);
    kp[p] = Kb + (size_t)g * DHc + half * 32 + q8g * 8;
    vp[p] = Vb + (size_t)row * Sc + half * 32 + q8g * 8;
    ldsOff[p] = cb * 8;
  }
  auto stage = [&](int buf) {
#pragma unroll
    for (int p = 0; p < 2; p++) {
      gld_lds16(kp[p], (f16*)Ks + buf * 4096 + ldsOff[p]);
      gld_lds16(vp[p], (f16*)Vs + buf * 4096 + ldsOff[p]);
      kp[p] += 64 * DHc;  // next chunk: 64 more key rows
      vp[p] += 64;        // next chunk: 64 more key columns
    }
  };

  // Q B-frags for 2 m-tiles; pre-scaled by 0.125*log2(e) in the GEMM epilogue.
  f16x8 qa[2][2];
#pragma unroll
  for (int mt = 0; mt < 2; mt++) {
    const f16* qb = Q + ((size_t)bh * Sc + qbase + mt * 16 + l16) * DHc;
    qa[mt][0] = *(const f16x8*)(qb + quad * 8);
    qa[mt][1] = *(const f16x8*)(qb + 32 + quad * 8);
  }

  // all-ones B-frag for the l row-sum MFMAs
  f16x8 ones;
#pragma unroll
  for (int j = 0; j < 8; j++) ones[j] = (f16)1.0f;

  // prologue: stage chunk 0; fill mask LDS (pre-scaled into exp2 domain)
  stage(0);
  {
    const float* mrow = mask + (size_t)b * Sc + t * 8;
    float4 a0 = *(const float4*)(mrow);
    float4 a1 = *(const float4*)(mrow + 4);
    *(f32x4*)(&Ms[t * 8]) = (f32x4){a0.x * L2E, a0.y * L2E, a0.z * L2E, a0.w * L2E};
    *(f32x4*)(&Ms[t * 8 + 4]) = (f32x4){a1.x * L2E, a1.y * L2E, a1.z * L2E, a1.w * L2E};
  }
  __syncthreads();

  f32x4 lacc[2];
  f32x4 o[2][4];
#pragma unroll
  for (int mt = 0; mt < 2; mt++) {
    lacc[mt] = (f32x4){0.f, 0.f, 0.f, 0.f};
#pragma unroll
    for (int dt = 0; dt < 4; dt++) o[mt][dt] = (f32x4){0.f, 0.f, 0.f, 0.f};
  }

  for (int c = 0; c < 32; c++) {
    const int buf = c & 1;
    if (c < 31) stage(buf ^ 1);

    // mask C-init from LDS (broadcast within quads, conflict-free across)
    const int mb = c * 64 + quad * 8;
    f32x4 minit[4];
    minit[0] = *(const f32x4*)(&Ms[mb + 0]);
    minit[1] = *(const f32x4*)(&Ms[mb + 4]);
    minit[2] = *(const f32x4*)(&Ms[mb + 32]);
    minit[3] = *(const f32x4*)(&Ms[mb + 36]);

    // K A-frags (staged/permuted rows), swizzled b128 positions
    f16x8 ka[4][2];
#pragma unroll
    for (int nt = 0; nt < 4; nt++) {
      int rb = (nt * 16 + l16) * 32 + qsw8;
      ka[nt][0] = *(const f16x8*)(&Ks[buf][rb]);
      ka[nt][1] = *(const f16x8*)(&Ks[buf][2048 + rb]);
    }

    // ---- QK both m-tiles: S^T = K*Q^T + mask (C-init), log2 domain ----
    f32x4 s0[4], s1[4];
#pragma unroll
    for (int nt = 0; nt < 4; nt++) {
      f32x4 a = minit[nt];
      a = MFMA16(ka[nt][0], qa[0][0], a);
      a = MFMA16(ka[nt][1], qa[0][1], a);
      s0[nt] = a;
      f32x4 a2 = minit[nt];
      a2 = MFMA16(ka[nt][0], qa[1][0], a2);
      a2 = MFMA16(ka[nt][1], qa[1][1], a2);
      s1[nt] = a2;
    }

    // ---- exp2 + pack: under the key permutation this IS the A-layout ----
    f16x8 pa[2][2];  // [mt][blk]
#pragma unroll
    for (int blk = 0; blk < 2; blk++) {
      f16x8 p0, p1;
#pragma unroll
      for (int half = 0; half < 2; half++) {
        int nt = blk * 2 + half;
#pragma unroll
        for (int r = 0; r < 4; r++) {
          p0[half * 4 + r] = (f16)__builtin_amdgcn_exp2f(s0[nt][r]);
          p1[half * 4 + r] = (f16)__builtin_amdgcn_exp2f(s1[nt][r]);
        }
      }
      pa[0][blk] = p0;
      pa[1][blk] = p1;
    }

    // ---- l row-sums on the MFMA pipe ----
    lacc[0] = MFMA16(pa[0][0], ones, lacc[0]);
    lacc[0] = MFMA16(pa[0][1], ones, lacc[0]);
    lacc[1] = MFMA16(pa[1][0], ones, lacc[1]);
    lacc[1] = MFMA16(pa[1][1], ones, lacc[1]);

    // ---- PV: 16x16x32, V b128 frags shared by both m-tiles ----
#pragma unroll
    for (int dt = 0; dt < 4; dt++) {
      int rb = (dt * 16 + l16) * 32 + qsw8;
      f16x8 v0 = *(const f16x8*)(&Vs[buf][rb]);
      f16x8 v1 = *(const f16x8*)(&Vs[buf][2048 + rb]);
      o[0][dt] = MFMA16(pa[0][0], v0, o[0][dt]);
      o[0][dt] = MFMA16(pa[0][1], v1, o[0][dt]);
      o[1][dt] = MFMA16(pa[1][0], v0, o[1][dt]);
      o[1][dt] = MFMA16(pa[1][1], v1, o[1][dt]);
    }

    __syncthreads();
  }

  // ---- epilogue: lacc D-layout rows (quad*4+r) == o rows; no shuffles ----
#pragma unroll
  for (int mt = 0; mt < 2; mt++) {
    float inv[4];
#pragma unroll
    for (int r = 0; r < 4; r++) inv[r] = 1.0f / lacc[mt][r];
#pragma unroll
    for (int dt = 0; dt < 4; dt++) {
      int col = h * 64 + dt * 16 + l16;
#pragma unroll
      for (int r = 0; r < 4; r++) {
        int row = qbase + mt * 16 + quad * 4 + r;
        out[((size_t)b * Sc + row) * Dc + col] = o[mt][dt][r] * inv[r];
      }
    }
  }
}

// ---------------------------------------------------------------------------
extern "C" void kernel_launch(void* const* d_in, const int* in_sizes, int n_in,
                              void* d_out, int out_size, void* d_ws,
                              size_t ws_size, hipStream_t stream) {
  (void)in_sizes; (void)n_in; (void)out_size; (void)ws_size;
  const float* hidden = (const float*)d_in[0];
  const float* mask   = (const float*)d_in[1];
  const float* Wq     = (const float*)d_in[2];
  const float* bq     = (const float*)d_in[3];
  const float* Wk     = (const float*)d_in[4];
  const float* bk     = (const float*)d_in[5];
  const float* Wv     = (const float*)d_in[6];
  const float* bv     = (const float*)d_in[7];
  float* out = (float*)d_out;

  uint8_t* w = (uint8_t*)d_ws;
  f16* Wt   = (f16*)(w);                               //  6 MB
  f16* X16  = (f16*)(w + (size_t)6 * 1024 * 1024);     // 16 MB
  f16* Q16  = (f16*)(w + (size_t)22 * 1024 * 1024);    // 16 MB (pre-scaled)
  f16* K16  = (f16*)(w + (size_t)38 * 1024 * 1024);    // 16 MB
  f16* Vt16 = (f16*)(w + (size_t)54 * 1024 * 1024);    // 16 MB, transposed

  cast_w_kernel<<<dim3(16, 16, 3), 256, 0, stream>>>(Wq, Wk, Wv, Wt);
  cast_x_kernel<<<4096, 256, 0, stream>>>(hidden, X16);
  qkv_gemm_kernel<<<dim3(1536), 256, 0, stream>>>(X16, Wt, bq, bk, bv,
                                                  Q16, K16, Vt16);
  flash_kernel<<<dim3(1024), 256, 0, stream>>>(Q16, K16, Vt16, mask, out);
}

// Round 12
// 253.971 us; speedup vs baseline: 1.0011x; 1.0011x over previous
//
#include <hip/hip_runtime.h>
#include <hip/hip_bf16.h>
#include <cstdint>

typedef _Float16 f16;
typedef f16 f16x8 __attribute__((ext_vector_type(8)));
typedef f16 f16x4 __attribute__((ext_vector_type(4)));
typedef float f32x4 __attribute__((ext_vector_type(4)));

#define MFMA16(a, b, c) __builtin_amdgcn_mfma_f32_16x16x32_f16((a), (b), (c), 0, 0, 0)

constexpr int Bc = 4, Sc = 2048, Dc = 1024, Hc = 16, DHc = 64;

typedef __attribute__((address_space(1))) const uint32_t gbl_u32;
typedef __attribute__((address_space(3))) uint32_t lds_u32;
__device__ __forceinline__ void gld_lds16(const void* g, void* l) {
  __builtin_amdgcn_global_load_lds((gbl_u32*)g, (lds_u32*)l, 16, 0, 0);
}

// ---------------------------------------------------------------------------
// Kernel 1: cast+transpose weights: W fp32 [K=1024][N=1024] -> Wt f16 [z][N][K]
// (viewed by the GEMM as one [3072][1024] B^T matrix)
// ---------------------------------------------------------------------------
__global__ __launch_bounds__(256) void cast_w_kernel(
    const float* __restrict__ Wq, const float* __restrict__ Wk,
    const float* __restrict__ Wv, f16* __restrict__ Wt) {
  __shared__ __align__(16) f16 T[64][66];
  const int z = blockIdx.z;
  const float* W = (z == 0) ? Wq : (z == 1) ? Wk : Wv;
  const int n0 = blockIdx.x * 64, k0 = blockIdx.y * 64;
  const int t = threadIdx.x;
#pragma unroll
  for (int p = 0; p < 4; p++) {
    int idx = t + p * 256;
    int r = idx >> 4, c = idx & 15;
    float4 v = *(const float4*)(W + (size_t)(k0 + r) * Dc + n0 + c * 4);
    T[r][c * 4 + 0] = (f16)v.x;
    T[r][c * 4 + 1] = (f16)v.y;
    T[r][c * 4 + 2] = (f16)v.z;
    T[r][c * 4 + 3] = (f16)v.w;
  }
  __syncthreads();
#pragma unroll
  for (int p = 0; p < 2; p++) {
    int idx = t + p * 256;
    int n = idx >> 3, c = idx & 7;
    f16x8 tmp;
#pragma unroll
    for (int j = 0; j < 8; j++) tmp[j] = T[c * 8 + j][n];
    *(f16x8*)(Wt + ((size_t)z * Dc + n0 + n) * Dc + k0 + c * 8) = tmp;
  }
}

// ---------------------------------------------------------------------------
// Kernel 1b: cast X fp32 -> f16.
// ---------------------------------------------------------------------------
__global__ __launch_bounds__(256) void cast_x_kernel(const float* __restrict__ X,
                                                     f16* __restrict__ X16) {
  size_t i = ((size_t)blockIdx.x * 256 + threadIdx.x) * 8;
  float4 a = *(const float4*)(X + i);
  float4 b = *(const float4*)(X + i + 4);
  f16x8 h;
  h[0] = (f16)a.x; h[1] = (f16)a.y; h[2] = (f16)a.z; h[3] = (f16)a.w;
  h[4] = (f16)b.x; h[5] = (f16)b.y; h[6] = (f16)b.z; h[7] = (f16)b.w;
  *(f16x8*)(X16 + i) = h;
}

// ---------------------------------------------------------------------------
// Kernel 2 (R12): R11's fused QKV GEMM + ONE delta: DOUBLE-BUFFERED K-loop
// (flash-proven pattern): stage(s+1)->buf^1, compute buf, ONE barrier/step.
// Barriers/block 64 -> 33; staging latency hides under the MFMA phase.
// Rationale: K=1024 = only 32 K-steps, so per-step barrier overhead is 4x
// the 4096^3 case where dbuf measured neutral (m99/m100) — regime differs.
// LDS 16 -> 32 KB; occupancy stays 4 blocks/CU (VGPR-bound).
// Epilogues unchanged from R11 (LDS-transpose Q/K, f16x4 V).
// XCD-chunked swizzle: lin&7 = XCD, m-tile innermost.
// Q pre-scaled by 0.125*log2(e) for the flash exp2 path.
// ---------------------------------------------------------------------------
__global__ __launch_bounds__(256) void qkv_gemm_kernel(
    const f16* __restrict__ X16, const f16* __restrict__ Wt,
    const float* __restrict__ bq, const float* __restrict__ bk,
    const float* __restrict__ bv, f16* __restrict__ Qo, f16* __restrict__ Ko,
    f16* __restrict__ Vo) {
  const int lin = blockIdx.x;               // 1536 blocks
  const int xcd = lin & 7, jj = lin >> 3;   // jj in [0,192)
  const int bn = jj >> 3;                   // 0..23 (n-tile over fused N=3072)
  const int bm = (xcd << 3) | (jj & 7);     // 0..63 (m-tile; inner index)
  const int z = bn >> 3;
  const int n0 = (bn & 7) * 128;            // col base within this z
  const int m0 = bm * 128;
  const f16* W = Wt + (size_t)bn * 128 * Dc;  // rows [bn*128, bn*128+128)
  const float* bias = (z == 0) ? bq : (z == 1) ? bk : bv;

  __shared__ __align__(16) f16 SMEM[16384];  // 32 KB: 2x(Xs+Ws) dbuf / Cbuf
  const int t = threadIdx.x;
  const int wave = t >> 6, lane = t & 63;
  const int l16 = lane & 15, quad = lane >> 4;
  const int wm = (wave >> 1) * 64, wn = (wave & 1) * 64;

  f32x4 acc[4][4];
#pragma unroll
  for (int i = 0; i < 4; i++)
#pragma unroll
    for (int j = 0; j < 4; j++) acc[i][j] = (f32x4){0.f, 0.f, 0.f, 0.f};

  auto stageG = [&](int k0, f16* Xd, f16* Wd) {
#pragma unroll
    for (int p = 0; p < 2; p++) {
      int cb = p * 256 + wave * 64;
      int chunk = cb + lane;
      int row = chunk >> 2, c8 = (chunk & 3) * 8;
      gld_lds16(X16 + (size_t)(m0 + row) * Dc + k0 + c8, Xd + (size_t)cb * 8);
      gld_lds16(W + (size_t)row * Dc + k0 + c8, Wd + (size_t)cb * 8);
    }
  };

  stageG(0, SMEM, SMEM + 4096);
  __syncthreads();

  for (int s = 0; s < 32; s++) {
    const int buf = s & 1;
    f16* Xs = SMEM + buf * 8192;
    f16* Ws = SMEM + buf * 8192 + 4096;
    if (s < 31)
      stageG((s + 1) * 32, SMEM + (buf ^ 1) * 8192,
             SMEM + (buf ^ 1) * 8192 + 4096);

    f16x8 aF[4], bF[4];
#pragma unroll
    for (int mt = 0; mt < 4; mt++)
      aF[mt] = *(const f16x8*)(&Xs[(wm + mt * 16 + l16) * 32 + quad * 8]);
#pragma unroll
    for (int nt = 0; nt < 4; nt++)
      bF[nt] = *(const f16x8*)(&Ws[(wn + nt * 16 + l16) * 32 + quad * 8]);
#pragma unroll
    for (int mt = 0; mt < 4; mt++)
#pragma unroll
      for (int nt = 0; nt < 4; nt++)
        acc[mt][nt] = MFMA16(aF[mt], bF[nt], acc[mt][nt]);
    // ONE barrier: drains next-step staging (compiler vmcnt) AND protects
    // buf for overwrite two steps out.
    __syncthreads();
  }

  if (z != 2) {
    // ---- LDS-transpose epilogue for Q/K (R11) ----
    const float sc = (z == 0) ? 0.18033688011112042f : 1.0f;  // Q: 0.125*log2e
    f16* O = (z == 0) ? Qo : Ko;
    const int wh = wave >> 1;  // which 64-row s-half this wave produced
    float bv4[4];
#pragma unroll
    for (int nt = 0; nt < 4; nt++) bv4[nt] = bias[n0 + wn + nt * 16 + l16];
    const int ridx = t >> 3, sub = t & 7;
    const int c0 = sub * 16;
    const int h = (n0 + c0) >> 6, d0 = c0 & 63;
#pragma unroll
    for (int mt = 0; mt < 4; mt++) {
#pragma unroll
      for (int nt = 0; nt < 4; nt++) {
        int c = wn + nt * 16 + l16;
#pragma unroll
        for (int r = 0; r < 4; r++) {
          int idx = wh * 16 + quad * 4 + r;
          SMEM[idx * 136 + c] = (f16)((acc[mt][nt][r] + bv4[nt]) * sc);
        }
      }
      __syncthreads();
      int s = m0 + (ridx >> 4) * 64 + mt * 16 + (ridx & 15);
      int b = s >> 11, sl = s & 2047;
      f16* dst = O + (((size_t)(b * Hc + h)) * Sc + sl) * DHc + d0;
      const f16* srcp = &SMEM[ridx * 136 + c0];
      f16x8 v0 = *(const f16x8*)(srcp);
      f16x8 v1 = *(const f16x8*)(srcp + 8);
      *(f16x8*)(dst) = v0;
      *(f16x8*)(dst + 8) = v1;
      __syncthreads();
    }
  } else {
    // ---- V epilogue (unchanged): f16x4 pack along s into Vt [bh][d][s] ----
#pragma unroll
    for (int nt = 0; nt < 4; nt++) {
      int col = n0 + wn + nt * 16 + l16;
      float bval = bias[col];
      int h = col >> 6, d = col & 63;
#pragma unroll
      for (int mt = 0; mt < 4; mt++) {
        int m = m0 + wm + mt * 16 + quad * 4;
        int b = m >> 11, sbase = m & 2047;
        f16x4 pk;
#pragma unroll
        for (int r = 0; r < 4; r++) pk[r] = (f16)(acc[mt][nt][r] + bval);
        *(f16x4*)(Vo + (((size_t)(b * Hc + h)) * DHc + d) * Sc + sbase) = pk;
      }
    }
  }
}

// ---------------------------------------------------------------------------
// Kernel 3 (R12): flash attention — unchanged from R3/R9/R10/R11 (measured
// 98-108 us band): 32 queries/wave, 1024 blocks = 4/CU, XCD-chunked bh,
// register-resident P via KEY-PERMUTED K staging, mask in LDS pre-scaled by
// log2(e), l row-sums on the MFMA pipe.
// ---------------------------------------------------------------------------
__global__ __launch_bounds__(256) void flash_kernel(
    const f16* __restrict__ Q, const f16* __restrict__ K,
    const f16* __restrict__ Vt, const float* __restrict__ mask,
    float* __restrict__ out) {
  const int lin = blockIdx.x;               // 1024 blocks
  const int xcd = lin & 7, jj = lin >> 3;   // jj in [0,128)
  const int bh = (xcd << 3) | (jj & 7);     // 0..63 (inner: bh cycles fastest)
  const int qt = jj >> 3;                   // 0..15
  const int b = bh >> 4, h = bh & 15;
  const int t = threadIdx.x;
  const int wave = t >> 6, lane = t & 63;
  const int l16 = lane & 15, quad = lane >> 4;
  const int qbase = qt * 128 + wave * 32;

  __shared__ __align__(16) f16 Ks[2][4096];  // [buf][half*2048+row*32+oct*8]
  __shared__ __align__(16) f16 Vs[2][4096];  // [buf][kh*2048+dh*32+oct*8]
  __shared__ __align__(16) float Ms[2048];   // mask row * log2(e)

  const f16* Kb = K + (size_t)bh * Sc * DHc;
  const f16* Vb = Vt + (size_t)bh * DHc * Sc;

  constexpr float L2E = 1.44269504088896340736f;

  // swizzled b128 read position (same for K and V frags)
  const int qsw8 = (quad ^ ((l16 >> 1) & 3)) * 8;

  // octet i -> half=i>>8, row=(i>>2)&63, pos q8=i&3 holds global octet
  // q8^((row>>1)&3). K rows are PERMUTED: staged row k holds global key
  // phys(k): [n1 n0 q1 q0 r1 r0] -> [n1 q1 q0 n0 r1 r0].
  const f16* kp[2];
  const f16* vp[2];
  int ldsOff[2];
#pragma unroll
  for (int p = 0; p < 2; p++) {
    int cb = p * 256 + wave * 64;  // wave-uniform octet base
    int i = cb + lane;
    int half = i >> 8, row = (i >> 2) & 63, q8 = i & 3;
    int q8g = q8 ^ ((row >> 1) & 3);
    int g = (row & 32) | ((row & 12) << 1) | ((row & 16) >> 2) | (row & 3);
    kp[p] = Kb + (size_t)g * DHc + half * 32 + q8g * 8;
    vp[p] = Vb + (size_t)row * Sc + half * 32 + q8g * 8;
    ldsOff[p] = cb * 8;
  }
  auto stage = [&](int buf) {
#pragma unroll
    for (int p = 0; p < 2; p++) {
      gld_lds16(kp[p], (f16*)Ks + buf * 4096 + ldsOff[p]);
      gld_lds16(vp[p], (f16*)Vs + buf * 4096 + ldsOff[p]);
      kp[p] += 64 * DHc;  // next chunk: 64 more key rows
      vp[p] += 64;        // next chunk: 64 more key columns
    }
  };

  // Q B-frags for 2 m-tiles; pre-scaled by 0.125*log2(e) in the GEMM epilogue.
  f16x8 qa[2][2];
#pragma unroll
  for (int mt = 0; mt < 2; mt++) {
    const f16* qb = Q + ((size_t)bh * Sc + qbase + mt * 16 + l16) * DHc;
    qa[mt][0] = *(const f16x8*)(qb + quad * 8);
    qa[mt][1] = *(const f16x8*)(qb + 32 + quad * 8);
  }

  // all-ones B-frag for the l row-sum MFMAs
  f16x8 ones;
#pragma unroll
  for (int j = 0; j < 8; j++) ones[j] = (f16)1.0f;

  // prologue: stage chunk 0; fill mask LDS (pre-scaled into exp2 domain)
  stage(0);
  {
    const float* mrow = mask + (size_t)b * Sc + t * 8;
    float4 a0 = *(const float4*)(mrow);
    float4 a1 = *(const float4*)(mrow + 4);
    *(f32x4*)(&Ms[t * 8]) = (f32x4){a0.x * L2E, a0.y * L2E, a0.z * L2E, a0.w * L2E};
    *(f32x4*)(&Ms[t * 8 + 4]) = (f32x4){a1.x * L2E, a1.y * L2E, a1.z * L2E, a1.w * L2E};
  }
  __syncthreads();

  f32x4 lacc[2];
  f32x4 o[2][4];
#pragma unroll
  for (int mt = 0; mt < 2; mt++) {
    lacc[mt] = (f32x4){0.f, 0.f, 0.f, 0.f};
#pragma unroll
    for (int dt = 0; dt < 4; dt++) o[mt][dt] = (f32x4){0.f, 0.f, 0.f, 0.f};
  }

  for (int c = 0; c < 32; c++) {
    const int buf = c & 1;
    if (c < 31) stage(buf ^ 1);

    // mask C-init from LDS (broadcast within quads, conflict-free across)
    const int mb = c * 64 + quad * 8;
    f32x4 minit[4];
    minit[0] = *(const f32x4*)(&Ms[mb + 0]);
    minit[1] = *(const f32x4*)(&Ms[mb + 4]);
    minit[2] = *(const f32x4*)(&Ms[mb + 32]);
    minit[3] = *(const f32x4*)(&Ms[mb + 36]);

    // K A-frags (staged/permuted rows), swizzled b128 positions
    f16x8 ka[4][2];
#pragma unroll
    for (int nt = 0; nt < 4; nt++) {
      int rb = (nt * 16 + l16) * 32 + qsw8;
      ka[nt][0] = *(const f16x8*)(&Ks[buf][rb]);
      ka[nt][1] = *(const f16x8*)(&Ks[buf][2048 + rb]);
    }

    // ---- QK both m-tiles: S^T = K*Q^T + mask (C-init), log2 domain ----
    f32x4 s0[4], s1[4];
#pragma unroll
    for (int nt = 0; nt < 4; nt++) {
      f32x4 a = minit[nt];
      a = MFMA16(ka[nt][0], qa[0][0], a);
      a = MFMA16(ka[nt][1], qa[0][1], a);
      s0[nt] = a;
      f32x4 a2 = minit[nt];
      a2 = MFMA16(ka[nt][0], qa[1][0], a2);
      a2 = MFMA16(ka[nt][1], qa[1][1], a2);
      s1[nt] = a2;
    }

    // ---- exp2 + pack: under the key permutation this IS the A-layout ----
    f16x8 pa[2][2];  // [mt][blk]
#pragma unroll
    for (int blk = 0; blk < 2; blk++) {
      f16x8 p0, p1;
#pragma unroll
      for (int half = 0; half < 2; half++) {
        int nt = blk * 2 + half;
#pragma unroll
        for (int r = 0; r < 4; r++) {
          p0[half * 4 + r] = (f16)__builtin_amdgcn_exp2f(s0[nt][r]);
          p1[half * 4 + r] = (f16)__builtin_amdgcn_exp2f(s1[nt][r]);
        }
      }
      pa[0][blk] = p0;
      pa[1][blk] = p1;
    }

    // ---- l row-sums on the MFMA pipe ----
    lacc[0] = MFMA16(pa[0][0], ones, lacc[0]);
    lacc[0] = MFMA16(pa[0][1], ones, lacc[0]);
    lacc[1] = MFMA16(pa[1][0], ones, lacc[1]);
    lacc[1] = MFMA16(pa[1][1], ones, lacc[1]);

    // ---- PV: 16x16x32, V b128 frags shared by both m-tiles ----
#pragma unroll
    for (int dt = 0; dt < 4; dt++) {
      int rb = (dt * 16 + l16) * 32 + qsw8;
      f16x8 v0 = *(const f16x8*)(&Vs[buf][rb]);
      f16x8 v1 = *(const f16x8*)(&Vs[buf][2048 + rb]);
      o[0][dt] = MFMA16(pa[0][0], v0, o[0][dt]);
      o[0][dt] = MFMA16(pa[0][1], v1, o[0][dt]);
      o[1][dt] = MFMA16(pa[1][0], v0, o[1][dt]);
      o[1][dt] = MFMA16(pa[1][1], v1, o[1][dt]);
    }

    __syncthreads();
  }

  // ---- epilogue: lacc D-layout rows (quad*4+r) == o rows; no shuffles ----
#pragma unroll
  for (int mt = 0; mt < 2; mt++) {
    float inv[4];
#pragma unroll
    for (int r = 0; r < 4; r++) inv[r] = 1.0f / lacc[mt][r];
#pragma unroll
    for (int dt = 0; dt < 4; dt++) {
      int col = h * 64 + dt * 16 + l16;
#pragma unroll
      for (int r = 0; r < 4; r++) {
        int row = qbase + mt * 16 + quad * 4 + r;
        out[((size_t)b * Sc + row) * Dc + col] = o[mt][dt][r] * inv[r];
      }
    }
  }
}

// ---------------------------------------------------------------------------
extern "C" void kernel_launch(void* const* d_in, const int* in_sizes, int n_in,
                              void* d_out, int out_size, void* d_ws,
                              size_t ws_size, hipStream_t stream) {
  (void)in_sizes; (void)n_in; (void)out_size; (void)ws_size;
  const float* hidden = (const float*)d_in[0];
  const float* mask   = (const float*)d_in[1];
  const float* Wq     = (const float*)d_in[2];
  const float* bq     = (const float*)d_in[3];
  const float* Wk     = (const float*)d_in[4];
  const float* bk     = (const float*)d_in[5];
  const float* Wv     = (const float*)d_in[6];
  const float* bv     = (const float*)d_in[7];
  float* out = (float*)d_out;

  uint8_t* w = (uint8_t*)d_ws;
  f16* Wt   = (f16*)(w);                               //  6 MB
  f16* X16  = (f16*)(w + (size_t)6 * 1024 * 1024);     // 16 MB
  f16* Q16  = (f16*)(w + (size_t)22 * 1024 * 1024);    // 16 MB (pre-scaled)
  f16* K16  = (f16*)(w + (size_t)38 * 1024 * 1024);    // 16 MB
  f16* Vt16 = (f16*)(w + (size_t)54 * 1024 * 1024);    // 16 MB, transposed

  cast_w_kernel<<<dim3(16, 16, 3), 256, 0, stream>>>(Wq, Wk, Wv, Wt);
  cast_x_kernel<<<4096, 256, 0, stream>>>(hidden, X16);
  qkv_gemm_kernel<<<dim3(1536), 256, 0, stream>>>(X16, Wt, bq, bk, bv,
                                                  Q16, K16, Vt16);
  flash_kernel<<<dim3(1024), 256, 0, stream>>>(Q16, K16, Vt16, mask, out);
}